// Round 10
// baseline (158.988 us; speedup 1.0000x reference)
//
#include <hip/hip_runtime.h>

#define B_TOT 4096
#define S_LEN 2048
#define U_ROW 2056
#define O_ROW 2057
#define PROW  2121   // padded LDS row: pos(g) = g + (g>>5), max 2119

// One recurrence step. u-args = window scalars u(s+1)..u(s+8); AR dep (w7*d7,
// d7 = previous acc) is LAST in the fmaf chain. Rotation is pure reg renaming.
#define ONE_STEP(A,B,C,D,E,F,G,H) { float acc = v0*(A);                    \
    acc=fmaf(v1,(B),acc); acc=fmaf(v2,(C),acc); acc=fmaf(v3,(D),acc);      \
    acc=fmaf(v4,(E),acc); acc=fmaf(v5,(F),acc); acc=fmaf(v6,(G),acc);      \
    acc=fmaf(v7,(H),acc);                                                  \
    acc=fmaf(w0,d0,acc); acc=fmaf(w1,d1,acc); acc=fmaf(w2,d2,acc);         \
    acc=fmaf(w3,d3,acc); acc=fmaf(w4,d4,acc); acc=fmaf(w5,d5,acc);         \
    acc=fmaf(w6,d6,acc); acc=fmaf(w7,d7,acc);                              \
    d0=d1;d1=d2;d2=d3;d3=d4;d4=d5;d5=d6;d6=d7;d7=acc; x+=acc; }

// 8 steps; if WR, stage x into own padded LDS band right after each step.
#define STEPS8(WR,OFS)                                                      \
    ONE_STEP(u1,u2,u3,u4,u5,u6,u7,u8)        if(WR) ub[b33+(OFS)+0]=x;      \
    ONE_STEP(u2,u3,u4,u5,u6,u7,u8,u9)        if(WR) ub[b33+(OFS)+1]=x;      \
    ONE_STEP(u3,u4,u5,u6,u7,u8,u9,u10)       if(WR) ub[b33+(OFS)+2]=x;      \
    ONE_STEP(u4,u5,u6,u7,u8,u9,u10,u11)      if(WR) ub[b33+(OFS)+3]=x;      \
    ONE_STEP(u5,u6,u7,u8,u9,u10,u11,u12)     if(WR) ub[b33+(OFS)+4]=x;      \
    ONE_STEP(u6,u7,u8,u9,u10,u11,u12,u13)    if(WR) ub[b33+(OFS)+5]=x;      \
    ONE_STEP(u7,u8,u9,u10,u11,u12,u13,u14)   if(WR) ub[b33+(OFS)+6]=x;      \
    ONE_STEP(u8,u9,u10,u11,u12,u13,u14,u15)  if(WR) ub[b33+(OFS)+7]=x;

#define SHIFT8() u0=u8;u1=u9;u2=u10;u3=u11;u4=u12;u5=u13;u6=u14;u7=u15;
#define REFILL(OFS) u8 =ub[b33+(OFS)+0]; u9 =ub[b33+(OFS)+1];               \
                    u10=ub[b33+(OFS)+2]; u11=ub[b33+(OFS)+3];               \
                    u12=ub[b33+(OFS)+4]; u13=ub[b33+(OFS)+5];               \
                    u14=ub[b33+(OFS)+6]; u15=ub[b33+(OFS)+7];

// 32 steps for chunk k. Tail (band k+1 overlap region) read BEFORE any write
// in program order (asm barrier pins compiler order; DS pipe per-wave
// in-order => cross-lane safe, R5/R8 proof). Own-band refills never collide.
#define RUN32(WR)                                                           \
    tl0=ub[b33+33]; tl1=ub[b33+34]; tl2=ub[b33+35]; tl3=ub[b33+36];         \
    tl4=ub[b33+37]; tl5=ub[b33+38]; tl6=ub[b33+39]; tl7=ub[b33+40];         \
    u0=ub[b33+0];  u1=ub[b33+1];  u2 =ub[b33+2];  u3 =ub[b33+3];            \
    u4=ub[b33+4];  u5=ub[b33+5];  u6 =ub[b33+6];  u7 =ub[b33+7];            \
    u8=ub[b33+8];  u9=ub[b33+9];  u10=ub[b33+10]; u11=ub[b33+11];           \
    u12=ub[b33+12];u13=ub[b33+13];u14=ub[b33+14]; u15=ub[b33+15];           \
    asm volatile("" ::: "memory");                                          \
    STEPS8(WR,0)  SHIFT8() REFILL(16)                                       \
    STEPS8(WR,8)  SHIFT8() REFILL(24)                                       \
    STEPS8(WR,16) SHIFT8() u8=tl0;u9=tl1;u10=tl2;u11=tl3;                   \
                           u12=tl4;u13=tl5;u14=tl6;u15=tl7;                 \
    STEPS8(WR,24)

// matvec row: DST = p1_i + T[i][:] . p2   (constant LDS offsets)
#define TROW(I,DST) { float a = p1_##I;                                     \
    a=fmaf(Tsh[(I)*8+0],p2_0,a); a=fmaf(Tsh[(I)*8+1],p2_1,a);               \
    a=fmaf(Tsh[(I)*8+2],p2_2,a); a=fmaf(Tsh[(I)*8+3],p2_3,a);               \
    a=fmaf(Tsh[(I)*8+4],p2_4,a); a=fmaf(Tsh[(I)*8+5],p2_5,a);               \
    a=fmaf(Tsh[(I)*8+6],p2_6,a); a=fmaf(Tsh[(I)*8+7],p2_7,a); DST = a; }

__global__ __launch_bounds__(256) void arix_fused(
    const float* __restrict__ y, const float* __restrict__ u,
    const float* __restrict__ W, float* __restrict__ out)
{
    __shared__ float ubuf[4][PROW];
    __shared__ float Tsh[64];     // T = A^32, [i*8+j]
    __shared__ float Gsh[8];      // sumG (x-response over 32 steps)
    const int lt = threadIdx.x;
    const int k  = lt & 63;
    const int w  = lt >> 6;
    const int b  = blockIdx.x * 4 + w;
    const int b33 = 33 * k;

    const float w0=W[0],w1=W[1],w2=W[2],w3=W[3],w4=W[4],w5=W[5],w6=W[6],w7=W[7];
    const float v0=W[8],v1=W[9],v2=W[10],v3=W[11],v4=W[12],v5=W[13],v6=W[14],v7=W[15];

    // ---- stage u row coalesced into padded per-wave LDS row ----
    const float4* up = (const float4*)(u + (long)b * U_ROW);
    float* ub = ubuf[w];
#pragma unroll
    for (int r = 0; r < 8; ++r) {
        float4 vv = up[r * 64 + k];
        const int g = (r * 64 + k) * 4;
        const int idx = g + (g >> 5);
        ub[idx] = vv.x; ub[idx + 1] = vv.y; ub[idx + 2] = vv.z; ub[idx + 3] = vv.w;
    }
    if (k < 2) {
        float4 vv = up[512 + k];
        const int g = (512 + k) * 4;
        const int idx = g + (g >> 5);
        ub[idx] = vv.x; ub[idx + 1] = vv.y; ub[idx + 2] = vv.z; ub[idx + 3] = vv.w;
    }

    // ---- y head (scalars) ----
    const long orow = (long)b * O_ROW;
    const float* yb = y + b * 9;
    const float y0=yb[0],y1=yb[1],y2=yb[2],y3=yb[3],y4=yb[4],
                y5=yb[5],y6=yb[6],y7=yb[7],y8=yb[8];
    if (k < 9) out[orow + k] = y[b * 9 + k];
    const float s0_0=y1-y0, s0_1=y2-y1, s0_2=y3-y2, s0_3=y4-y3,
                s0_4=y5-y4, s0_5=y6-y5, s0_6=y7-y6, s0_7=y8-y7;
    const float x0 = y8;

    // ---- T = A^32 columns + sumG via unit responses (lanes 0..7) ----
    if (lt < 8) {
        float r0=(lt==0)?1.f:0.f, r1=(lt==1)?1.f:0.f, r2=(lt==2)?1.f:0.f,
              r3=(lt==3)?1.f:0.f, r4=(lt==4)?1.f:0.f, r5=(lt==5)?1.f:0.f,
              r6=(lt==6)?1.f:0.f, r7=(lt==7)?1.f:0.f, xs=0.f;
        for (int t = 0; t < 32; ++t) {
            float a = w0*r0; a=fmaf(w1,r1,a); a=fmaf(w2,r2,a); a=fmaf(w3,r3,a);
            a=fmaf(w4,r4,a); a=fmaf(w5,r5,a); a=fmaf(w6,r6,a); a=fmaf(w7,r7,a);
            r0=r1;r1=r2;r2=r3;r3=r4;r4=r5;r5=r6;r6=r7;r7=a; xs+=a;
        }
        Tsh[0*8+lt]=r0; Tsh[1*8+lt]=r1; Tsh[2*8+lt]=r2; Tsh[3*8+lt]=r3;
        Tsh[4*8+lt]=r4; Tsh[5*8+lt]=r5; Tsh[6*8+lt]=r6; Tsh[7*8+lt]=r7;
        Gsh[lt]=xs;
    }
    __syncthreads();   // the only block barrier

    // ---- phase 1: zero-state chunk recurrence ----
    float d0=0.f,d1=0.f,d2=0.f,d3=0.f,d4=0.f,d5=0.f,d6=0.f,d7=0.f, x=0.f;
    float u0,u1,u2,u3,u4,u5,u6,u7,u8,u9,u10,u11,u12,u13,u14,u15;
    float tl0,tl1,tl2,tl3,tl4,tl5,tl6,tl7;
    RUN32(0)

    // ---- truncated combine: s_k = P_{k-1} + T*P_{k-2} (||A^64|| ~ 1e-8) ----
    const float Q = x;
    float p1_0=__shfl_up(d0,1), p1_1=__shfl_up(d1,1), p1_2=__shfl_up(d2,1),
          p1_3=__shfl_up(d3,1), p1_4=__shfl_up(d4,1), p1_5=__shfl_up(d5,1),
          p1_6=__shfl_up(d6,1), p1_7=__shfl_up(d7,1);
    float p2_0=__shfl_up(d0,2), p2_1=__shfl_up(d1,2), p2_2=__shfl_up(d2,2),
          p2_3=__shfl_up(d3,2), p2_4=__shfl_up(d4,2), p2_5=__shfl_up(d5,2),
          p2_6=__shfl_up(d6,2), p2_7=__shfl_up(d7,2);
    p2_0=(k==1)?s0_0:p2_0; p2_1=(k==1)?s0_1:p2_1; p2_2=(k==1)?s0_2:p2_2;
    p2_3=(k==1)?s0_3:p2_3; p2_4=(k==1)?s0_4:p2_4; p2_5=(k==1)?s0_5:p2_5;
    p2_6=(k==1)?s0_6:p2_6; p2_7=(k==1)?s0_7:p2_7;
    float n0,n1,n2,n3,n4,n5,n6,n7;
    TROW(0,n0) TROW(1,n1) TROW(2,n2) TROW(3,n3)
    TROW(4,n4) TROW(5,n5) TROW(6,n6) TROW(7,n7)
    n0=(k==0)?s0_0:n0; n1=(k==0)?s0_1:n1; n2=(k==0)?s0_2:n2; n3=(k==0)?s0_3:n3;
    n4=(k==0)?s0_4:n4; n5=(k==0)?s0_5:n5; n6=(k==0)?s0_6:n6; n7=(k==0)?s0_7:n7;

    float dx = Q;
    dx=fmaf(Gsh[0],n0,dx); dx=fmaf(Gsh[1],n1,dx); dx=fmaf(Gsh[2],n2,dx);
    dx=fmaf(Gsh[3],n3,dx); dx=fmaf(Gsh[4],n4,dx); dx=fmaf(Gsh[5],n5,dx);
    dx=fmaf(Gsh[6],n6,dx); dx=fmaf(Gsh[7],n7,dx);
#pragma unroll
    for (int l = 0; l < 6; ++l) {
        const int delta = 1 << l;
        float t = __shfl_up(dx, delta);
        dx += (k >= delta) ? t : 0.f;
    }
    const float ex = __shfl_up(dx, 1);
    x = x0 + ((k == 0) ? 0.f : ex);
    d0=n0; d1=n1; d2=n2; d3=n3; d4=n4; d5=n5; d6=n6; d7=n7;

    // ---- phase 3: true recurrence, x staged into LDS band ----
    RUN32(1)

    // ---- coalesced writeback (cross-lane reads AFTER all writes) ----
    asm volatile("" ::: "memory");
#pragma unroll 4
    for (int r = 0; r < 33; ++r) {
        const int pz = r * 64 + k;
        if (pz >= 9 && pz < O_ROW) {
            const int g = pz - 9;
            out[orow + pz] = ub[g + (g >> 5)];
        }
    }
}

extern "C" void kernel_launch(void* const* d_in, const int* in_sizes, int n_in,
                              void* d_out, int out_size, void* d_ws, size_t ws_size,
                              hipStream_t stream) {
    const float* y = (const float*)d_in[0];
    const float* u = (const float*)d_in[1];
    const float* W = (const float*)d_in[2];
    float* out = (float*)d_out;

    // MEASUREMENT ROUND: 4 identical idempotent launches. dur = OH + 4K,
    // combined with R9 (dur = OH + K) solves both unknowns exactly.
    // Kernel reads only u/y/W (never modified) and writes out
    // deterministically, so replaying it 4x leaves the identical, correct
    // output. All launches on `stream`; graph-capture safe.
    arix_fused<<<dim3(B_TOT / 4), dim3(256), 0, stream>>>(y, u, W, out);
    arix_fused<<<dim3(B_TOT / 4), dim3(256), 0, stream>>>(y, u, W, out);
    arix_fused<<<dim3(B_TOT / 4), dim3(256), 0, stream>>>(y, u, W, out);
    arix_fused<<<dim3(B_TOT / 4), dim3(256), 0, stream>>>(y, u, W, out);
}

// Round 11
// 97.182 us; speedup vs baseline: 1.6360x; 1.6360x over previous
//
#include <hip/hip_runtime.h>

#define B_TOT 4096
#define HALF_B 2048
#define U_ROW 2056
#define O_ROW 2057
#define PROW  2121   // padded LDS row: pos(g) = g + (g>>5), max 2119

// One recurrence step; AR dep (w7*d7) last; rotation = register renaming.
#define ONE_STEP(A,B,C,D,E,F,G,H) { float acc = v0*(A);                    \
    acc=fmaf(v1,(B),acc); acc=fmaf(v2,(C),acc); acc=fmaf(v3,(D),acc);      \
    acc=fmaf(v4,(E),acc); acc=fmaf(v5,(F),acc); acc=fmaf(v6,(G),acc);      \
    acc=fmaf(v7,(H),acc);                                                  \
    acc=fmaf(w0,d0,acc); acc=fmaf(w1,d1,acc); acc=fmaf(w2,d2,acc);         \
    acc=fmaf(w3,d3,acc); acc=fmaf(w4,d4,acc); acc=fmaf(w5,d5,acc);         \
    acc=fmaf(w6,d6,acc); acc=fmaf(w7,d7,acc);                              \
    d0=d1;d1=d2;d2=d3;d3=d4;d4=d5;d5=d6;d6=d7;d7=acc; x+=acc; }

#define STEPS8(WR,OFS)                                                      \
    ONE_STEP(u1,u2,u3,u4,u5,u6,u7,u8)        if(WR) ubp[b33+(OFS)+0]=x;     \
    ONE_STEP(u2,u3,u4,u5,u6,u7,u8,u9)        if(WR) ubp[b33+(OFS)+1]=x;     \
    ONE_STEP(u3,u4,u5,u6,u7,u8,u9,u10)       if(WR) ubp[b33+(OFS)+2]=x;     \
    ONE_STEP(u4,u5,u6,u7,u8,u9,u10,u11)      if(WR) ubp[b33+(OFS)+3]=x;     \
    ONE_STEP(u5,u6,u7,u8,u9,u10,u11,u12)     if(WR) ubp[b33+(OFS)+4]=x;     \
    ONE_STEP(u6,u7,u8,u9,u10,u11,u12,u13)    if(WR) ubp[b33+(OFS)+5]=x;     \
    ONE_STEP(u7,u8,u9,u10,u11,u12,u13,u14)   if(WR) ubp[b33+(OFS)+6]=x;     \
    ONE_STEP(u8,u9,u10,u11,u12,u13,u14,u15)  if(WR) ubp[b33+(OFS)+7]=x;

#define SHIFT8() u0=u8;u1=u9;u2=u10;u3=u11;u4=u12;u5=u13;u6=u14;u7=u15;
#define REFILL(OFS) u8 =ubp[b33+(OFS)+0]; u9 =ubp[b33+(OFS)+1];             \
                    u10=ubp[b33+(OFS)+2]; u11=ubp[b33+(OFS)+3];             \
                    u12=ubp[b33+(OFS)+4]; u13=ubp[b33+(OFS)+5];             \
                    u14=ubp[b33+(OFS)+6]; u15=ubp[b33+(OFS)+7];

// 32 steps for chunk k. Cross-lane tail read BEFORE any write in program
// order (same wave => lockstep instruction stream; DS pipe in-order). R5/R8.
#define RUN32(WR)                                                           \
    tl0=ubp[b33+33]; tl1=ubp[b33+34]; tl2=ubp[b33+35]; tl3=ubp[b33+36];     \
    tl4=ubp[b33+37]; tl5=ubp[b33+38]; tl6=ubp[b33+39]; tl7=ubp[b33+40];     \
    u0=ubp[b33+0];  u1=ubp[b33+1];  u2 =ubp[b33+2];  u3 =ubp[b33+3];        \
    u4=ubp[b33+4];  u5=ubp[b33+5];  u6 =ubp[b33+6];  u7 =ubp[b33+7];        \
    u8=ubp[b33+8];  u9=ubp[b33+9];  u10=ubp[b33+10]; u11=ubp[b33+11];       \
    u12=ubp[b33+12];u13=ubp[b33+13];u14=ubp[b33+14]; u15=ubp[b33+15];       \
    asm volatile("" ::: "memory");                                          \
    STEPS8(WR,0)  SHIFT8() REFILL(16)                                       \
    STEPS8(WR,8)  SHIFT8() REFILL(24)                                       \
    STEPS8(WR,16) SHIFT8() u8=tl0;u9=tl1;u10=tl2;u11=tl3;                   \
                           u12=tl4;u13=tl5;u14=tl6;u15=tl7;                 \
    STEPS8(WR,24)

#define TROW(I,DST) { float a = p1_##I;                                     \
    a=fmaf(Tsh[(I)*8+0],p2_0,a); a=fmaf(Tsh[(I)*8+1],p2_1,a);               \
    a=fmaf(Tsh[(I)*8+2],p2_2,a); a=fmaf(Tsh[(I)*8+3],p2_3,a);               \
    a=fmaf(Tsh[(I)*8+4],p2_4,a); a=fmaf(Tsh[(I)*8+5],p2_5,a);               \
    a=fmaf(Tsh[(I)*8+6],p2_6,a); a=fmaf(Tsh[(I)*8+7],p2_7,a); DST = a; }

// Truncated combine (R8-proven): s_k = P_{k-1} + T*P_{k-2}, ||A^64|| ~ 1e-8.
#define COMBINE() {                                                         \
    const float Q = x;                                                      \
    float p1_0=__shfl_up(d0,1), p1_1=__shfl_up(d1,1), p1_2=__shfl_up(d2,1), \
          p1_3=__shfl_up(d3,1), p1_4=__shfl_up(d4,1), p1_5=__shfl_up(d5,1), \
          p1_6=__shfl_up(d6,1), p1_7=__shfl_up(d7,1);                       \
    float p2_0=__shfl_up(d0,2), p2_1=__shfl_up(d1,2), p2_2=__shfl_up(d2,2), \
          p2_3=__shfl_up(d3,2), p2_4=__shfl_up(d4,2), p2_5=__shfl_up(d5,2), \
          p2_6=__shfl_up(d6,2), p2_7=__shfl_up(d7,2);                       \
    p2_0=(k==1)?s0_0:p2_0; p2_1=(k==1)?s0_1:p2_1; p2_2=(k==1)?s0_2:p2_2;    \
    p2_3=(k==1)?s0_3:p2_3; p2_4=(k==1)?s0_4:p2_4; p2_5=(k==1)?s0_5:p2_5;    \
    p2_6=(k==1)?s0_6:p2_6; p2_7=(k==1)?s0_7:p2_7;                           \
    float n0,n1,n2,n3,n4,n5,n6,n7;                                          \
    TROW(0,n0) TROW(1,n1) TROW(2,n2) TROW(3,n3)                             \
    TROW(4,n4) TROW(5,n5) TROW(6,n6) TROW(7,n7)                             \
    n0=(k==0)?s0_0:n0; n1=(k==0)?s0_1:n1; n2=(k==0)?s0_2:n2;                \
    n3=(k==0)?s0_3:n3; n4=(k==0)?s0_4:n4; n5=(k==0)?s0_5:n5;                \
    n6=(k==0)?s0_6:n6; n7=(k==0)?s0_7:n7;                                   \
    float dx = Q;                                                           \
    dx=fmaf(Gsh[0],n0,dx); dx=fmaf(Gsh[1],n1,dx); dx=fmaf(Gsh[2],n2,dx);    \
    dx=fmaf(Gsh[3],n3,dx); dx=fmaf(Gsh[4],n4,dx); dx=fmaf(Gsh[5],n5,dx);    \
    dx=fmaf(Gsh[6],n6,dx); dx=fmaf(Gsh[7],n7,dx);                           \
    _Pragma("unroll")                                                       \
    for (int l = 0; l < 6; ++l) {                                           \
        const int delta = 1 << l;                                           \
        float t = __shfl_up(dx, delta);                                     \
        dx += (k >= delta) ? t : 0.f;                                       \
    }                                                                       \
    const float ex = __shfl_up(dx, 1);                                      \
    x = x0 + ((k == 0) ? 0.f : ex);                                         \
    d0=n0; d1=n1; d2=n2; d3=n3; d4=n4; d5=n5; d6=n6; d7=n7; }

// Coalesced writeback, nontemporal (write-once stream, bypass L2).
#define WRITEBACK(OROW)                                                     \
    asm volatile("" ::: "memory");                                          \
    _Pragma("unroll 4")                                                     \
    for (int r = 0; r < 33; ++r) {                                          \
        const int pz = r * 64 + k;                                          \
        if (pz >= 9 && pz < O_ROW) {                                        \
            const int g = pz - 9;                                           \
            __builtin_nontemporal_store(ubp[g + (g >> 5)], &out[(OROW) + pz]); \
        }                                                                   \
    }

// 128-thread blocks, 2 waves; each wave pipelines TWO rows (gid, gid+2048):
// stage A -> compute A -> issue B global loads -> writeback A (overlaps with
// B reads in flight) -> ds_write B -> compute B -> writeback B.
__global__ __launch_bounds__(128) void arix_fused(
    const float* __restrict__ y, const float* __restrict__ u,
    const float* __restrict__ W, float* __restrict__ out)
{
    __shared__ float ubuf[4][PROW];   // wave w: [2w] = row A, [2w+1] = row B
    __shared__ float Tsh[64];         // T = A^32
    __shared__ float Gsh[8];          // sumG
    const int lt = threadIdx.x;
    const int k  = lt & 63;
    const int w  = lt >> 6;
    const int gid = blockIdx.x * 2 + w;      // row A; row B = gid + 2048
    const int b33 = 33 * k;

    const float w0=W[0],w1=W[1],w2=W[2],w3=W[3],w4=W[4],w5=W[5],w6=W[6],w7=W[7];
    const float v0=W[8],v1=W[9],v2=W[10],v3=W[11],v4=W[12],v5=W[13],v6=W[14],v7=W[15];

    float* ubp = ubuf[2 * w];

    // ---- stage row A into LDS (coalesced float4, padded) ----
    {
        const float4* up = (const float4*)(u + (long)gid * U_ROW);
#pragma unroll
        for (int r = 0; r < 8; ++r) {
            float4 vv = up[r * 64 + k];
            const int g = (r * 64 + k) * 4;
            const int idx = g + (g >> 5);
            ubp[idx] = vv.x; ubp[idx+1] = vv.y; ubp[idx+2] = vv.z; ubp[idx+3] = vv.w;
        }
        if (k < 2) {
            float4 vv = up[512 + k];
            const int g = (512 + k) * 4;
            const int idx = g + (g >> 5);
            ubp[idx] = vv.x; ubp[idx+1] = vv.y; ubp[idx+2] = vv.z; ubp[idx+3] = vv.w;
        }
    }

    // ---- T = A^32 columns + sumG (lanes 0..7 of wave 0) ----
    if (lt < 8) {
        float r0=(lt==0)?1.f:0.f, r1=(lt==1)?1.f:0.f, r2=(lt==2)?1.f:0.f,
              r3=(lt==3)?1.f:0.f, r4=(lt==4)?1.f:0.f, r5=(lt==5)?1.f:0.f,
              r6=(lt==6)?1.f:0.f, r7=(lt==7)?1.f:0.f, xs=0.f;
        for (int t = 0; t < 32; ++t) {
            float a = w0*r0; a=fmaf(w1,r1,a); a=fmaf(w2,r2,a); a=fmaf(w3,r3,a);
            a=fmaf(w4,r4,a); a=fmaf(w5,r5,a); a=fmaf(w6,r6,a); a=fmaf(w7,r7,a);
            r0=r1;r1=r2;r2=r3;r3=r4;r4=r5;r5=r6;r6=r7;r7=a; xs+=a;
        }
        Tsh[0*8+lt]=r0; Tsh[1*8+lt]=r1; Tsh[2*8+lt]=r2; Tsh[3*8+lt]=r3;
        Tsh[4*8+lt]=r4; Tsh[5*8+lt]=r5; Tsh[6*8+lt]=r6; Tsh[7*8+lt]=r7;
        Gsh[lt]=xs;
    }
    __syncthreads();   // the only block barrier

    float u0,u1,u2,u3,u4,u5,u6,u7,u8,u9,u10,u11,u12,u13,u14,u15;
    float tl0,tl1,tl2,tl3,tl4,tl5,tl6,tl7;
    float d0,d1,d2,d3,d4,d5,d6,d7, x;
    float s0_0,s0_1,s0_2,s0_3,s0_4,s0_5,s0_6,s0_7, x0;

    // ---- row A head ----
    long orow = (long)gid * O_ROW;
    {
        const float* yb = y + gid * 9;
        const float y0=yb[0],y1=yb[1],y2=yb[2],y3=yb[3],y4=yb[4],
                    y5=yb[5],y6=yb[6],y7=yb[7],y8=yb[8];
        if (k < 9) out[orow + k] = y[gid * 9 + k];
        s0_0=y1-y0; s0_1=y2-y1; s0_2=y3-y2; s0_3=y4-y3;
        s0_4=y5-y4; s0_5=y6-y5; s0_6=y7-y6; s0_7=y8-y7;
        x0 = y8;
    }

    // ---- row A compute ----
    d0=0.f;d1=0.f;d2=0.f;d3=0.f;d4=0.f;d5=0.f;d6=0.f;d7=0.f; x=0.f;
    RUN32(0)
    COMBINE()
    RUN32(1)

    // ---- issue row B global loads NOW (in flight during A writeback) ----
    const int bB = gid + HALF_B;
    float4 bs0,bs1,bs2,bs3,bs4,bs5,bs6,bs7,bs8;
    bs8 = make_float4(0.f,0.f,0.f,0.f);
    {
        const float4* upB = (const float4*)(u + (long)bB * U_ROW);
        bs0 = upB[0*64+k]; bs1 = upB[1*64+k]; bs2 = upB[2*64+k];
        bs3 = upB[3*64+k]; bs4 = upB[4*64+k]; bs5 = upB[5*64+k];
        bs6 = upB[6*64+k]; bs7 = upB[7*64+k];
        if (k < 2) bs8 = upB[512 + k];
    }
    const float* ybB = y + bB * 9;
    const float yB0=ybB[0],yB1=ybB[1],yB2=ybB[2],yB3=ybB[3],yB4=ybB[4],
                yB5=ybB[5],yB6=ybB[6],yB7=ybB[7],yB8=ybB[8];

    // ---- writeback A (NT stores; B loads outstanding) ----
    WRITEBACK(orow)

    // ---- row B: LDS stage from regs, head, compute, writeback ----
    ubp = ubuf[2 * w + 1];
    {
#pragma unroll
        for (int r = 0; r < 8; ++r) {
            float4 vv = (r==0)?bs0:(r==1)?bs1:(r==2)?bs2:(r==3)?bs3:
                        (r==4)?bs4:(r==5)?bs5:(r==6)?bs6:bs7;
            const int g = (r * 64 + k) * 4;
            const int idx = g + (g >> 5);
            ubp[idx] = vv.x; ubp[idx+1] = vv.y; ubp[idx+2] = vv.z; ubp[idx+3] = vv.w;
        }
        if (k < 2) {
            const int g = (512 + k) * 4;
            const int idx = g + (g >> 5);
            ubp[idx] = bs8.x; ubp[idx+1] = bs8.y; ubp[idx+2] = bs8.z; ubp[idx+3] = bs8.w;
        }
    }
    orow = (long)bB * O_ROW;
    if (k < 9) out[orow + k] = y[bB * 9 + k];
    s0_0=yB1-yB0; s0_1=yB2-yB1; s0_2=yB3-yB2; s0_3=yB4-yB3;
    s0_4=yB5-yB4; s0_5=yB6-yB5; s0_6=yB7-yB6; s0_7=yB8-yB7;
    x0 = yB8;

    d0=0.f;d1=0.f;d2=0.f;d3=0.f;d4=0.f;d5=0.f;d6=0.f;d7=0.f; x=0.f;
    RUN32(0)
    COMBINE()
    RUN32(1)

    WRITEBACK(orow)
}

extern "C" void kernel_launch(void* const* d_in, const int* in_sizes, int n_in,
                              void* d_out, int out_size, void* d_ws, size_t ws_size,
                              hipStream_t stream) {
    const float* y = (const float*)d_in[0];
    const float* u = (const float*)d_in[1];
    const float* W = (const float*)d_in[2];
    float* out = (float*)d_out;

    arix_fused<<<dim3(HALF_B / 2), dim3(128), 0, stream>>>(y, u, W, out);
}